// Round 8
// baseline (209.393 us; speedup 1.0000x reference)
//
#include <hip/hip_runtime.h>

// ---------------------------------------------------------------------------
// EncoderLayer on MI355X (gfx950).
// D=512, H=8, DK=64, DF=2048, B=2, S=2048, N=B*S=4096 tokens.
// R8: combine fused into Wo GEMM A-staging (po/ls -> normalize -> LDS);
// QKV V^T epilogue via LDS transpose + coalesced stores; prep vectorized.
// ---------------------------------------------------------------------------

#define Dm   512
#define Hh   8
#define DKk  64
#define DFf  2048
#define Bb   2
#define Ss   2048
#define Nn   4096   // B*S

typedef __attribute__((ext_vector_type(8))) short short8;   // 8 bf16 = 4 VGPR
typedef __attribute__((ext_vector_type(4))) float f32x4;
typedef __attribute__((ext_vector_type(4))) short short4v;
typedef __attribute__((ext_vector_type(2))) int   int2v;

__device__ inline float bf2f(short s) {
    unsigned u = ((unsigned)(unsigned short)s) << 16;
    float f; __builtin_memcpy(&f, &u, 4); return f;
}
__device__ inline short f2bf(float f) {
    unsigned u; __builtin_memcpy(&u, &f, 4);
    u = (u + 0x7fff + ((u >> 16) & 1)) >> 16;   // RNE
    return (short)u;
}
__device__ inline short cvt_elem(const void* p, long i, int f32flag) {
    if (f32flag) return f2bf(((const float*)p)[i]);
    return ((const short*)p)[i];
}
// uniform per-block dtype detect (bf16 pairs misread as f32 -> implausible)
__device__ inline int detect_f32(const void* x) {
    const float* xf = (const float*)x;
    int ok = 0;
#pragma unroll
    for (int i = 0; i < 16; ++i) {
        float a = fabsf(xf[i]);
        ok += (a > 1e-8f && a < 1e4f) ? 1 : 0;
    }
    return ok >= 8;
}
// async global->LDS, 16 B per lane (LDS dest = wave-uniform base + lane*16)
__device__ inline void gload_lds16(const short* g, short* l) {
    __builtin_amdgcn_global_load_lds(
        (const __attribute__((address_space(1))) unsigned int*)g,
        (__attribute__((address_space(3))) unsigned int*)l, 16, 0, 0);
}

// ---------------------------------------------------------------------------
// Prep: canonicalize x + small arrays (blocks 0..512) and transpose weights
// (blocks 513..1280) into canonical bf16 Wt[col][k]. bf16 fast path uses
// short8 global loads/stores; f32 path scalar.
// smalls: bq@0 bk@512 bv@1024 bo@1536 b1@2048 b2@4096 g1@4608 be1@5120
//         g2@5632 be2@6144
// ---------------------------------------------------------------------------
__global__ __launch_bounds__(256) void prep_kernel(
    const void* __restrict__ x, short* __restrict__ xb,
    const void* bq, const void* bk, const void* bv, const void* bo,
    const void* b1, const void* b2, const void* g1, const void* be1,
    const void* g2, const void* be2, short* __restrict__ smalls,
    const void* Wq, const void* Wk, const void* Wv,
    const void* Wo, const void* W1, const void* W2,
    short* __restrict__ WqkvT,
    short* __restrict__ WoT, short* __restrict__ W1T, short* __restrict__ W2T)
{
    const int f = detect_f32(x);
    int blk = blockIdx.x;
    if (blk < 512) {
        long base = (long)blk * 4096;
        if (!f) {
            const short8* src8 = (const short8*)((const short*)x + base);
            short8* dst8 = (short8*)(xb + base);
            for (int i = threadIdx.x; i < 512; i += 256) dst8[i] = src8[i];
        } else {
            for (int i = threadIdx.x; i < 4096; i += 256)
                xb[base + i] = cvt_elem(x, base + i, f);
        }
        return;
    }
    if (blk == 512) {
        const void* srcs[10] = {bq, bk, bv, bo, b1, b2, g1, be1, g2, be2};
        const int   sz[10]   = {512, 512, 512, 512, 2048, 512, 512, 512, 512, 512};
        int off = 0;
        for (int j = 0; j < 10; ++j) {
            for (int i = threadIdx.x; i < sz[j]; i += 256)
                smalls[off + i] = cvt_elem(srcs[j], i, f);
            off += sz[j];
        }
        return;
    }
    __shared__ short tile[64][65];
    blk -= 513;
    const void* src; short* dst; long srcoff = 0; long dstoff = 0; int R, C, tr, tc;
    if (blk < 192) {
        int m = blk >> 6; int r = blk & 63; int h = r >> 3; int t = r & 7;
        src = (m == 0) ? Wq : (m == 1) ? Wk : Wv;
        dst = WqkvT + (long)m * 512 * 512;
        srcoff = (long)h * 512 * 64; dstoff = (long)h * 64 * 512;
        R = 512; C = 64; tr = t; tc = 0;
    } else if (blk < 256) {
        int r = blk - 192; src = Wo; dst = WoT; R = 512; C = 512; tr = r >> 3; tc = r & 7;
    } else if (blk < 512) {
        int r = blk - 256; src = W1; dst = W1T; R = 512; C = 2048; tr = r >> 5; tc = r & 31;
    } else {
        int r = blk - 512; src = W2; dst = W2T; R = 2048; C = 512; tr = r >> 3; tc = r & 7;
    }
    int r0 = tr * 64, c0 = tc * 64;
    if (!f) {
        const short* s16 = (const short*)src;
        for (int i = threadIdx.x; i < 512; i += 256) {
            int rr = i >> 3, c8 = (i & 7) * 8;
            short8 v = *(const short8*)&s16[srcoff + (long)(r0 + rr) * C + c0 + c8];
#pragma unroll
            for (int j = 0; j < 8; ++j) tile[rr][c8 + j] = v[j];
        }
        __syncthreads();
        for (int i = threadIdx.x; i < 512; i += 256) {
            int cc = i >> 3, r8 = (i & 7) * 8;
            short8 w;
#pragma unroll
            for (int j = 0; j < 8; ++j) w[j] = tile[r8 + j][cc];
            *(short8*)&dst[dstoff + (long)(c0 + cc) * R + r0 + r8] = w;
        }
    } else {
        for (int i = threadIdx.x; i < 4096; i += 256) {
            int rr = i >> 6, cc = i & 63;
            tile[rr][cc] = cvt_elem(src, srcoff + (long)(r0 + rr) * C + c0 + cc, f);
        }
        __syncthreads();
        for (int i = threadIdx.x; i < 4096; i += 256) {
            int cc = i >> 6, rr = i & 63;
            dst[dstoff + (long)(c0 + cc) * R + r0 + rr] = tile[rr][cc];
        }
    }
}

// ---------------------------------------------------------------------------
// GEMM: C = A[M][K] @ Bt[Ncols][K]^T + bias.
// 256 thr (4 waves 2x2), tile 128x128, BK=64, double-buffered DMA staging.
// MODE_QKV: Q out *0.125; V out transposed via LDS (coalesced V^T stores).
// ---------------------------------------------------------------------------
#define MODE_F32       1
#define MODE_RELU_BF16 2
#define MODE_QKV       4

__global__ __launch_bounds__(256) void gemm_kernel(
    const short* __restrict__ A, const short* __restrict__ Bt,
    const short* __restrict__ bias, void* __restrict__ outp,
    void* __restrict__ out2, void* __restrict__ out3,
    int K, int Ncols, int mode, int Ktile)
{
    __shared__ short As[2][128 * 64];
    __shared__ short Bs[2][128 * 64];
    const int t    = threadIdx.x;
    const int lane = t & 63;
    const int wave = t >> 6;
    const int quad = lane >> 4;
    const int l15  = lane & 15;
    const int wm = wave >> 1, wn = wave & 1;
    const int row0 = blockIdx.x * 128;
    const int col0 = blockIdx.y * 128;
    const int kbase = blockIdx.z * Ktile;

    const int ri = lane >> 3;
    const int ct = (lane & 7) ^ ri;

    f32x4 acc[4][4];
#pragma unroll
    for (int i = 0; i < 4; ++i)
#pragma unroll
        for (int j = 0; j < 4; ++j) acc[i][j] = (f32x4){0.f, 0.f, 0.f, 0.f};

    auto stage = [&](int buf, int k0) {
#pragma unroll
        for (int p = 0; p < 4; ++p) {
            int r = wave * 32 + p * 8;
            gload_lds16(A + (long)(row0 + r + ri) * K + kbase + k0 + ct * 8,
                        &As[buf][r * 64 + lane * 8]);
        }
#pragma unroll
        for (int p = 0; p < 4; ++p) {
            int r = wave * 32 + p * 8;
            gload_lds16(Bt + (long)(col0 + r + ri) * K + kbase + k0 + ct * 8,
                        &Bs[buf][r * 64 + lane * 8]);
        }
    };

    stage(0, 0);
    int cur = 0;
    const int niter = Ktile >> 6;
    for (int it = 0; it < niter; ++it) {
        asm volatile("s_waitcnt vmcnt(0)" ::: "memory");
        __syncthreads();
        if (it + 1 < niter) stage(cur ^ 1, (it + 1) * 64);
#pragma unroll
        for (int kk = 0; kk < 2; ++kk) {
            short8 af[4], bfr[4];
#pragma unroll
            for (int mt = 0; mt < 4; ++mt) {
                int rowa = wm * 64 + mt * 16 + l15;
                af[mt] = *(const short8*)&As[cur][rowa * 64
                              + (((kk * 4 + quad) ^ (rowa & 7)) * 8)];
            }
#pragma unroll
            for (int nt = 0; nt < 4; ++nt) {
                int rowb = wn * 64 + nt * 16 + l15;
                bfr[nt] = *(const short8*)&Bs[cur][rowb * 64
                              + (((kk * 4 + quad) ^ (rowb & 7)) * 8)];
            }
#pragma unroll
            for (int mt = 0; mt < 4; ++mt)
#pragma unroll
                for (int nt = 0; nt < 4; ++nt)
                    acc[mt][nt] = __builtin_amdgcn_mfma_f32_16x16x32_bf16(
                        af[mt], bfr[nt], acc[mt][nt], 0, 0, 0);
        }
        cur ^= 1;
    }

    const int wrow0 = row0 + wm * 64;
    const int wcol0 = col0 + wn * 64;
    // C/D layout: row = quad*4 + r, col = l15 (measured m89/m91)
    if (mode == MODE_QKV) {
        if (wcol0 < 1024) {   // Q (scaled 0.125) and K, token-major
            int m = wcol0 >> 9;
            short* out = (short*)(m == 0 ? outp : out2);
            float sc = (m == 0) ? 0.125f : 1.0f;
#pragma unroll
            for (int nt = 0; nt < 4; ++nt) {
                int col = wcol0 + nt * 16 + l15;
                float bb = bf2f(bias[col]);
                int cl = col & 511;
#pragma unroll
                for (int mt = 0; mt < 4; ++mt)
#pragma unroll
                    for (int r = 0; r < 4; ++r) {
                        int row = wrow0 + mt * 16 + quad * 4 + r;
                        out[(long)row * 512 + cl] = f2bf((acc[mt][nt][r] + bb) * sc);
                    }
            }
        } else {
            // V block: transpose 128x128 tile through LDS, store V^T coalesced.
            __syncthreads();                     // all waves done with As
            short* Asf = &As[0][0];              // 16384 shorts = 32 KB
#pragma unroll
            for (int nt = 0; nt < 4; ++nt) {
                int col_l = wn * 64 + nt * 16 + l15;      // 0..127
                float bb = bf2f(bias[col0 + col_l]);
#pragma unroll
                for (int mt = 0; mt < 4; ++mt) {
                    int row4 = wm * 16 + mt * 4 + quad;   // row_local>>2
                    int slot = row4 ^ (col_l & 31);
                    short4v pk;
#pragma unroll
                    for (int r = 0; r < 4; ++r) pk[r] = f2bf(acc[mt][nt][r] + bb);
                    *(short4v*)&Asf[col_l * 128 + slot * 4] = pk;
                }
            }
            __syncthreads();
            short* out = (short*)out3;
            int col_l = t >> 1;
            int cl = col0 + col_l - 1024;
            int hh = cl >> 6, kk2 = cl & 63;
            int bg = row0 >> 11;
            long obase = ((long)(bg * Hh + hh) * DKk + kk2) * Ss + (row0 & 2047);
#pragma unroll
            for (int i = 0; i < 8; ++i) {
                int chunk = (t & 1) * 8 + i;              // 0..15
                int s0 = (chunk * 2)     ^ (col_l & 31);
                int s1 = (chunk * 2 + 1) ^ (col_l & 31);
                short4v a = *(const short4v*)&Asf[col_l * 128 + s0 * 4];
                short4v b4 = *(const short4v*)&Asf[col_l * 128 + s1 * 4];
                short8 w;
                w[0] = a[0];  w[1] = a[1];  w[2] = a[2];  w[3] = a[3];
                w[4] = b4[0]; w[5] = b4[1]; w[6] = b4[2]; w[7] = b4[3];
                *(short8*)&out[obase + chunk * 8] = w;
            }
        }
    } else if (mode == MODE_F32) {
        float* out = (float*)outp + (long)blockIdx.z * Nn * Ncols;
        int zb = (blockIdx.z == 0);
#pragma unroll
        for (int nt = 0; nt < 4; ++nt) {
            int col = wcol0 + nt * 16 + l15;
            float bb = zb ? bf2f(bias[col]) : 0.f;
#pragma unroll
            for (int mt = 0; mt < 4; ++mt)
#pragma unroll
                for (int r = 0; r < 4; ++r) {
                    int row = wrow0 + mt * 16 + quad * 4 + r;
                    out[(long)row * Ncols + col] = acc[mt][nt][r] + bb;
                }
        }
    } else {   // MODE_RELU_BF16
        short* out = (short*)outp;
#pragma unroll
        for (int nt = 0; nt < 4; ++nt) {
            int col = wcol0 + nt * 16 + l15;
            float bb = bf2f(bias[col]);
#pragma unroll
            for (int mt = 0; mt < 4; ++mt)
#pragma unroll
                for (int r = 0; r < 4; ++r) {
                    int row = wrow0 + mt * 16 + quad * 4 + r;
                    out[(long)row * Ncols + col] = f2bf(fmaxf(acc[mt][nt][r] + bb, 0.f));
                }
        }
    }
}

// ---------------------------------------------------------------------------
// Wo GEMM with fused attention combine: attnout = (sum_ks po / sum_ks ls) @ Wo.
// grid (32 token-tiles, 4 col-tiles, 2 split-K). Each BK=64 K-slice == one
// head h = z*4+it; A-tile built in-register from 4 bf16 po partials + ls,
// normalized, ds_write_b128 into swizzled LDS. B via DMA double-buffer.
// f32 partial outputs (2) summed in LN1.
// ---------------------------------------------------------------------------
__global__ __launch_bounds__(256) void wogemm_kernel(
    const short* __restrict__ po, const float* __restrict__ ls,
    const short* __restrict__ Bt, const short* __restrict__ bias,
    float* __restrict__ outp)
{
    __shared__ short As[2][128 * 64];
    __shared__ short Bs[2][128 * 64];
    const int t    = threadIdx.x;
    const int lane = t & 63;
    const int wave = t >> 6;
    const int quad = lane >> 4;
    const int l15  = lane & 15;
    const int wm = wave >> 1, wn = wave & 1;
    const int row0 = blockIdx.x * 128;
    const int col0 = blockIdx.y * 128;
    const int z    = blockIdx.z;

    const int ri = lane >> 3;
    const int ct = (lane & 7) ^ ri;
    const int myrow = t >> 1;          // 0..127 (one token row per thread)
    const int tcb = (t & 1) * 4;       // chunk base 0 or 4
    const int bg = row0 >> 11;
    const int qtl = (row0 >> 7) & 15;

    f32x4 acc[4][4];
#pragma unroll
    for (int i = 0; i < 4; ++i)
#pragma unroll
        for (int j = 0; j < 4; ++j) acc[i][j] = (f32x4){0.f, 0.f, 0.f, 0.f};

    auto stageB = [&](int buf, int k0) {
#pragma unroll
        for (int p = 0; p < 4; ++p) {
            int r = wave * 32 + p * 8;
            gload_lds16(Bt + (long)(col0 + r + ri) * 512 + z * 256 + k0 + ct * 8,
                        &Bs[buf][r * 64 + lane * 8]);
        }
    };

    short8 aR[4][4];   // [chunk c][ks]
    float  lR[4];
    auto loadA = [&](int it) {
        int h = z * 4 + it;
        long pbase = ((long)(bg * Hh + h) * 16 + qtl) * 4;
#pragma unroll
        for (int ks = 0; ks < 4; ++ks) {
            lR[ks] = ls[(pbase + ks) * 128 + myrow];
#pragma unroll
            for (int c = 0; c < 4; ++c)
                aR[c][ks] = *(const short8*)&po[((pbase + ks) * 128 + myrow) * 64
                                                + (tcb + c) * 8];
        }
    };
    auto cvtwrite = [&](int buf) {
        float invL = __builtin_amdgcn_rcpf(lR[0] + lR[1] + lR[2] + lR[3]);
#pragma unroll
        for (int c = 0; c < 4; ++c) {
            short8 w;
#pragma unroll
            for (int j = 0; j < 8; ++j) {
                float s = bf2f(aR[c][0][j]) + bf2f(aR[c][1][j])
                        + bf2f(aR[c][2][j]) + bf2f(aR[c][3][j]);
                w[j] = f2bf(s * invL);
            }
            int slot = (tcb + c) ^ (myrow & 7);
            *(short8*)&As[buf][myrow * 64 + slot * 8] = w;
        }
    };

    loadA(0); stageB(0, 0); cvtwrite(0);
    int cur = 0;
#pragma unroll
    for (int it = 0; it < 4; ++it) {
        __syncthreads();   // compiler drains vmcnt+lgkmcnt before s_barrier
        if (it < 3) { loadA(it + 1); stageB(cur ^ 1, (it + 1) * 64); }
#pragma unroll
        for (int kk = 0; kk < 2; ++kk) {
            short8 af[4], bfr[4];
#pragma unroll
            for (int mt = 0; mt < 4; ++mt) {
                int rowa = wm * 64 + mt * 16 + l15;
                af[mt] = *(const short8*)&As[cur][rowa * 64
                              + (((kk * 4 + quad) ^ (rowa & 7)) * 8)];
            }
#pragma unroll
            for (int nt = 0; nt < 4; ++nt) {
                int rowb = wn * 64 + nt * 16 + l15;
                bfr[nt] = *(const short8*)&Bs[cur][rowb * 64
                              + (((kk * 4 + quad) ^ (rowb & 7)) * 8)];
            }
#pragma unroll
            for (int mt = 0; mt < 4; ++mt)
#pragma unroll
                for (int nt = 0; nt < 4; ++nt)
                    acc[mt][nt] = __builtin_amdgcn_mfma_f32_16x16x32_bf16(
                        af[mt], bfr[nt], acc[mt][nt], 0, 0, 0);
        }
        if (it < 3) cvtwrite(cur ^ 1);
        cur ^= 1;
    }

    const int wrow0 = row0 + wm * 64;
    const int wcol0 = col0 + wn * 64;
    float* out = outp + (long)z * Nn * Dm;
    int zb = (z == 0);
#pragma unroll
    for (int nt = 0; nt < 4; ++nt) {
        int col = wcol0 + nt * 16 + l15;
        float bb = zb ? bf2f(bias[col]) : 0.f;
#pragma unroll
        for (int mt = 0; mt < 4; ++mt)
#pragma unroll
            for (int r = 0; r < 4; ++r) {
                int row = wrow0 + mt * 16 + quad * 4 + r;
                out[(long)row * Dm + col] = acc[mt][nt][r] + bb;
            }
    }
}

// ---------------------------------------------------------------------------
// Flash attention (R7). grid (16 qt, 16 bh, 4 ks), 256 thr, 32 q/wave,
// 8 iters of 64 KV. Single-buffer K/V LDS (DMA w16, XOR swizzle), S^T = K·Q^T
// so exp packs in-register (v_perm) -> b64 P stores; lsum scalar/qh.
// Unnormalized bf16 po + f32 ls partials, additive over ks.
// ---------------------------------------------------------------------------
__global__ __launch_bounds__(256) void attn_kernel(
    const short* __restrict__ Q, const short* __restrict__ Kt,
    const short* __restrict__ Vt, short* __restrict__ po, float* __restrict__ ls)
{
    __shared__ __align__(16) short Ks[64 * 64];
    __shared__ __align__(16) short Vs[64 * 64];
    __shared__ __align__(16) short pbuf[4][32 * 72];
    const int lane = threadIdx.x & 63;
    const int wave = threadIdx.x >> 6;
    const int quad = lane >> 4;
    const int l15  = lane & 15;
    const int qt = blockIdx.x, bh = blockIdx.y, ks = blockIdx.z;
    const int b = bh >> 3, h = bh & 7;
    const int qrow = b * Ss + qt * 128 + wave * 32;

    short8 bq[2][2];
#pragma unroll
    for (int qh = 0; qh < 2; ++qh)
#pragma unroll
        for (int kk = 0; kk < 2; ++kk)
            bq[qh][kk] = *(const short8*)(Q + (long)(qrow + qh * 16 + l15) * Dm
                                          + h * DKk + kk * 32 + quad * 8);

    f32x4 o[2][4];
    float lsum[2] = {0.f, 0.f};
#pragma unroll
    for (int qh = 0; qh < 2; ++qh)
#pragma unroll
        for (int nt = 0; nt < 4; ++nt) o[qh][nt] = (f32x4){0.f, 0.f, 0.f, 0.f};

    const short* Kg = Kt + (long)b * Ss * Dm + h * DKk;
    const short* Vg = Vt + (long)bh * DKk * Ss;
    short* pbw = pbuf[wave];
    const int t00 = ks * 512;

    const int ri = lane >> 3;
    const int ct = (lane & 7) ^ ri;
    const int ldsrow0 = wave * 16;

    for (int it = 0; it < 8; ++it) {
        const int t0 = t00 + it * 64;
#pragma unroll
        for (int p = 0; p < 2; ++p) {
            int r = ldsrow0 + p * 8 + ri;
            gload_lds16(Kg + (long)(t0 + r) * Dm + ct * 8,
                        &Ks[(ldsrow0 + p * 8) * 64] + lane * 8);
        }
#pragma unroll
        for (int p = 0; p < 2; ++p) {
            int r = ldsrow0 + p * 8 + ri;
            gload_lds16(Vg + (long)r * Ss + t0 + ct * 8,
                        &Vs[(ldsrow0 + p * 8) * 64] + lane * 8);
        }
        asm volatile("s_waitcnt vmcnt(0)" ::: "memory");
        __syncthreads();

#pragma unroll
        for (int j = 0; j < 4; ++j) {
            short8 kf0 = *(const short8*)&Ks[(j * 16 + l15) * 64
                                             + ((quad ^ (l15 & 7)) * 8)];
            short8 kf1 = *(const short8*)&Ks[(j * 16 + l15) * 64
                                             + (((4 + quad) ^ (l15 & 7)) * 8)];
#pragma unroll
            for (int qh = 0; qh < 2; ++qh) {
                f32x4 sj = (f32x4){0.f, 0.f, 0.f, 0.f};
                sj = __builtin_amdgcn_mfma_f32_16x16x32_bf16(kf0, bq[qh][0], sj, 0, 0, 0);
                sj = __builtin_amdgcn_mfma_f32_16x16x32_bf16(kf1, bq[qh][1], sj, 0, 0, 0);
                int2v pk;
#pragma unroll
                for (int r2 = 0; r2 < 2; ++r2) {
                    float pa = __expf(fminf(sj[r2 * 2 + 0], 20.f));
                    float pc = __expf(fminf(sj[r2 * 2 + 1], 20.f));
                    lsum[qh] += pa + pc;
                    unsigned ua, uc;
                    __builtin_memcpy(&ua, &pa, 4);
                    __builtin_memcpy(&uc, &pc, 4);
                    pk[r2] = __builtin_amdgcn_perm(uc, ua, 0x07060302);
                }
                *(int2v*)&pbw[(qh * 16 + l15) * 72 + j * 16 + quad * 4] = pk;
            }
        }
        asm volatile("s_waitcnt lgkmcnt(0)" ::: "memory");
#pragma unroll
        for (int c = 0; c < 2; ++c) {
            short8 ap[2];
#pragma unroll
            for (int qh = 0; qh < 2; ++qh)
                ap[qh] = *(const short8*)&pbw[(qh * 16 + l15) * 72 + c * 32 + quad * 8];
#pragma unroll
            for (int nt = 0; nt < 4; ++nt) {
                short8 vf = *(const short8*)&Vs[(nt * 16 + l15) * 64
                                                + (((c * 4 + quad) ^ (l15 & 7)) * 8)];
#pragma unroll
                for (int qh = 0; qh < 2; ++qh)
                    o[qh][nt] = __builtin_amdgcn_mfma_f32_16x16x32_bf16(
                        ap[qh], vf, o[qh][nt], 0, 0, 0);
            }
        }
        asm volatile("" ::: "memory");
        __syncthreads();
    }

#pragma unroll
    for (int qh = 0; qh < 2; ++qh) {
        float v = lsum[qh];
        v += __shfl_xor(v, 16);
        v += __shfl_xor(v, 32);
        lsum[qh] = v;
    }
    short* pob = po + ((((long)bh * 16 + qt) * 4 + ks) * 128) * 64;
#pragma unroll
    for (int qh = 0; qh < 2; ++qh)
#pragma unroll
        for (int nt = 0; nt < 4; ++nt)
#pragma unroll
            for (int r = 0; r < 4; ++r)
                pob[(wave * 32 + qh * 16 + quad * 4 + r) * 64 + nt * 16 + l15] =
                    f2bf(o[qh][nt][r]);
    if (lane < 16) {
        long lbase = (((long)bh * 16 + qt) * 4 + ks) * 128 + wave * 32;
        ls[lbase + l15]      = lsum[0];
        ls[lbase + 16 + l15] = lsum[1];
    }
}

// ---------------------------------------------------------------------------
// Residual + LayerNorm, up to 4 f32 partial inputs + bf16 residual.
// xdet != null: detect output dtype from xdet (LN2 writes d_out).
// ---------------------------------------------------------------------------
__global__ __launch_bounds__(256) void ln_kernel(
    const float* __restrict__ v0, const float* __restrict__ v1,
    const float* __restrict__ v2, const float* __restrict__ v3,
    const short* __restrict__ res,
    const short* __restrict__ g, const short* __restrict__ bt,
    void* __restrict__ out, const void* __restrict__ xdet)
{
    const int row = blockIdx.x, tid = threadIdx.x;
    const long base = (long)row * Dm;
    const long i0 = base + tid, i1 = base + 256 + tid;
    float x0 = v0[i0] + bf2f(res[i0]);
    float x1 = v0[i1] + bf2f(res[i1]);
    if (v1) { x0 += v1[i0]; x1 += v1[i1]; }
    if (v2) { x0 += v2[i0]; x1 += v2[i1]; }
    if (v3) { x0 += v3[i0]; x1 += v3[i1]; }

    __shared__ float red[8];
    const int wv = tid >> 6, ln = tid & 63;
    float s = x0 + x1;
#pragma unroll
    for (int mk = 1; mk < 64; mk <<= 1) s += __shfl_xor(s, mk);
    if (!ln) red[wv] = s;
    __syncthreads();
    float mean = (red[0] + red[1] + red[2] + red[3]) * (1.f / 512.f);
    float d0 = x0 - mean, d1 = x1 - mean;
    float q = d0 * d0 + d1 * d1;
#pragma unroll
    for (int mk = 1; mk < 64; mk <<= 1) q += __shfl_xor(q, mk);
    if (!ln) red[4 + wv] = q;
    __syncthreads();
    float rs = rsqrtf((red[4] + red[5] + red[6] + red[7]) * (1.f / 512.f) + 1e-5f);
    float y0 = d0 * rs * bf2f(g[tid])       + bf2f(bt[tid]);
    float y1 = d1 * rs * bf2f(g[256 + tid]) + bf2f(bt[256 + tid]);
    int f32out = xdet ? detect_f32(xdet) : 0;
    if (f32out) {
        float* o = (float*)out;
        o[i0] = y0; o[i1] = y1;
    } else {
        short* o = (short*)out;
        o[i0] = f2bf(y0); o[i1] = f2bf(y1);
    }
}

// ---------------------------------------------------------------------------
extern "C" void kernel_launch(void* const* d_in, const int* in_sizes, int n_in,
                              void* d_out, int out_size, void* d_ws, size_t ws_size,
                              hipStream_t stream)
{
    (void)in_sizes; (void)n_in; (void)out_size; (void)ws_size;
    const void* x   = d_in[0];
    const void* Wq  = d_in[1];  const void* bq  = d_in[2];
    const void* Wk  = d_in[3];  const void* bk  = d_in[4];
    const void* Wv  = d_in[5];  const void* bv  = d_in[6];
    const void* Wo  = d_in[7];  const void* bo  = d_in[8];
    const void* g1  = d_in[9];  const void* be1 = d_in[10];
    const void* W1  = d_in[11]; const void* b1  = d_in[12];
    const void* W2  = d_in[13]; const void* b2  = d_in[14];
    const void* g2  = d_in[15]; const void* be2 = d_in[16];

    char* ws = (char*)d_ws;
    size_t off = 0;
    auto alloc = [&](size_t bytes) -> void* {
        void* p = ws + off; off += (bytes + 255) & ~(size_t)255; return p;
    };
    short* WqkvT = (short*)alloc((size_t)3 * Dm * Dm * 2);   // [1536][512]
    short* WoT   = (short*)alloc((size_t)Dm * Dm * 2);
    short* W1T   = (short*)alloc((size_t)DFf * Dm * 2);
    short* W2T   = (short*)alloc((size_t)Dm * DFf * 2);
    short* xb    = (short*)alloc((size_t)Nn * Dm * 2);
    short* sm    = (short*)alloc((size_t)6656 * 2);
    // region A (16 MB): Qb/Kb/Vt; u overlays after attention is consumed
    char*  regA  = (char*)alloc((size_t)Nn * DFf * 2);
    short* Qb    = (short*)(regA);
    short* Kb    = (short*)(regA + (size_t)Nn * Dm * 2);
    short* Vt    = (short*)(regA + (size_t)Nn * Dm * 4);
    short* u     = (short*)(regA);
    // region B (16 MB): Wo split-K=2 f32 partials
    float* wo_p  = (float*)alloc((size_t)2 * Nn * Dm * 4);
    // region C (32 MB): attn bf16 partials po; FFN2 split-K=4 f32 partials
    // overlay (disjoint lifetimes)
    char*  regC  = (char*)alloc((size_t)4 * Nn * Dm * 4);
    short* po    = (short*)regC;
    float* f2p   = (float*)regC;
    float* lsb   = (float*)alloc((size_t)16 * 16 * 4 * 128 * 4);
    short* h_bf  = (short*)alloc((size_t)Nn * Dm * 2);

    prep_kernel<<<1281, 256, 0, stream>>>(x, xb, bq, bk, bv, bo, b1, b2,
                                          g1, be1, g2, be2, sm,
                                          Wq, Wk, Wv, Wo, W1, W2,
                                          WqkvT, WoT, W1T, W2T);
    // fused QKV projection: [4096][512] @ [1536][512]^T
    gemm_kernel<<<dim3(Nn / 128, 1536 / 128, 1), 256, 0, stream>>>(
        xb, WqkvT, sm + 0, Qb, Kb, Vt, Dm, 1536, MODE_QKV, Dm);
    attn_kernel<<<dim3(Ss / 128, Bb * Hh, 4), 256, 0, stream>>>(Qb, Kb, Vt, po, lsb);
    // Wo projection with fused combine, split-K=2 -> f32 partials
    wogemm_kernel<<<dim3(Nn / 128, Dm / 128, 2), 256, 0, stream>>>(
        po, lsb, WoT, sm + 1536, wo_p);
    ln_kernel<<<Nn, 256, 0, stream>>>(wo_p, wo_p + (long)Nn * Dm, nullptr, nullptr,
                                      xb, sm + 4608, sm + 5120, h_bf, nullptr);
    gemm_kernel<<<dim3(Nn / 128, DFf / 128, 1), 256, 0, stream>>>(
        h_bf, W1T, sm + 2048, u, nullptr, nullptr, Dm, DFf, MODE_RELU_BF16, Dm);
    // FFN2, split-K=4 -> f32 partials
    gemm_kernel<<<dim3(Nn / 128, Dm / 128, 4), 256, 0, stream>>>(
        u, W2T, sm + 4096, f2p, nullptr, nullptr, DFf, Dm, MODE_F32, DFf / 4);
    ln_kernel<<<Nn, 256, 0, stream>>>(f2p, f2p + (long)Nn * Dm, f2p + (long)2 * Nn * Dm,
                                      f2p + (long)3 * Nn * Dm,
                                      h_bf, sm + 5632, sm + 6144, d_out, x);
}